// Round 17
// baseline (544.300 us; speedup 1.0000x reference)
//
#include <hip/hip_runtime.h>
#include <hip/hip_bf16.h>

// DF-HGNN fused pipeline v17 = v16 + nontemporal hints on streaming no-reuse
// traffic (Hbp stores/loads, pbuf stores/loads) to stop L2 pollution.
// N=20000, E=4096, IN=512, DET=256, HID=256, HALF=128, OUT=2.

typedef __bf16 bf16_t;
typedef __attribute__((ext_vector_type(8))) __bf16 bf16x8;
typedef __attribute__((ext_vector_type(4))) __bf16 bf16x4;
typedef __attribute__((ext_vector_type(4))) float f32x4;
typedef __attribute__((ext_vector_type(2))) float f32x2;

#define NN 20000
#define NE 4096
#define NNP 20480           // 640*32 padded node extent
#define AT_S 16             // n-split for H^T @ Y
#define NEB 4               // e-blocks in stats grid (1024 cols each)
#define NNB 160             // n-blocks in stats grid (128 rows each)
// Layouts:
//  Hbp [p=e>>6][n][e&63]               : column-panel-tiled bf16 H
//  Yf  [fblk 16][nblk 640][lane 64][8] : value(f,n) at lane=((n&31)>>3)*16+(f&15), j=n&7
//  Hef [fblk 16][eblk 128][lane 64][8] : value(f,e) same scheme with k=e
//  part[s][tile=eblk16*16+fblk][lane 64][4]

__device__ __forceinline__ f32x4 mfma16(bf16x8 a, bf16x8 b, f32x4 c) {
  return __builtin_amdgcn_mfma_f32_16x16x32_bf16(a, b, c, 0, 0, 0);
}

// nontemporal 16B/8B access helpers (streaming, no L2 reuse)
__device__ __forceinline__ void nt_store16(bf16_t* p, bf16x8 v) {
  __builtin_nontemporal_store(__builtin_bit_cast(f32x4, v), (f32x4*)p);
}
__device__ __forceinline__ bf16x8 nt_load16(const bf16_t* p) {
  return __builtin_bit_cast(bf16x8, __builtin_nontemporal_load((const f32x4*)p));
}
__device__ __forceinline__ void nt_store8(bf16_t* p, bf16x4 v) {
  __builtin_nontemporal_store(__builtin_bit_cast(f32x2, v), (f32x2*)p);
}
__device__ __forceinline__ bf16x4 nt_load8(const bf16_t* p) {
  return __builtin_bit_cast(bf16x4, __builtin_nontemporal_load((const f32x2*)p));
}

// ---------------- stats body (vbx 0..3 x 1024 cols, vby 0..159 x 128 rows) -
__device__ __forceinline__ void stats_body(int vbx, int vby,
    const float* __restrict__ H, const float* __restrict__ w,
    float* __restrict__ Dvp, float* __restrict__ Dep, bf16_t* __restrict__ Hbp,
    float (*dvl)[17], float (*deP)[1024]) {
  int t = threadIdx.x, l = t & 63, wv = t >> 6;
  long e0 = (long)vbx * 1024;
  long n0 = (long)vby * 128;
  long pA = ((e0 >> 6) + (l >> 3)) * (long)NNP;
  long pB = (((e0 + 512) >> 6) + (l >> 3)) * (long)NNP;
  int inner = (l & 7) * 8;
  f32x4 wa0 = *(const f32x4*)(w + e0 + l * 8);
  f32x4 wa1 = *(const f32x4*)(w + e0 + l * 8 + 4);
  f32x4 wb0 = *(const f32x4*)(w + e0 + 512 + l * 8);
  f32x4 wb1 = *(const f32x4*)(w + e0 + 512 + l * 8 + 4);
  f32x4 deA0, deA1, deB0, deB1;
  deA0 = deA1 = deB0 = deB1 = f32x4{0.f, 0.f, 0.f, 0.f};
  const float* ha = H + e0 + l * 8;
  const float* hb = H + e0 + 512 + l * 8;
  #pragma unroll 4
  for (int i = 0; i < 32; ++i) {
    long row = n0 + wv * 32 + i;
    float s;
    if (row < NN) {
      f32x4 ua0 = *(const f32x4*)(ha + row * NE);
      f32x4 ua1 = *(const f32x4*)(ha + row * NE + 4);
      f32x4 ub0 = *(const f32x4*)(hb + row * NE);
      f32x4 ub1 = *(const f32x4*)(hb + row * NE + 4);
      bf16x8 pa, pb;
      #pragma unroll
      for (int j = 0; j < 4; ++j) {
        pa[j] = (__bf16)ua0[j]; pa[4 + j] = (__bf16)ua1[j];
        pb[j] = (__bf16)ub0[j]; pb[4 + j] = (__bf16)ub1[j];
      }
      nt_store16(Hbp + (pA + row) * 64 + inner, pa);
      nt_store16(Hbp + (pB + row) * 64 + inner, pb);
      deA0 += ua0; deA1 += ua1; deB0 += ub0; deB1 += ub1;
      s = ua0[0]*wa0[0] + ua0[1]*wa0[1] + ua0[2]*wa0[2] + ua0[3]*wa0[3]
        + ua1[0]*wa1[0] + ua1[1]*wa1[1] + ua1[2]*wa1[2] + ua1[3]*wa1[3]
        + ub0[0]*wb0[0] + ub0[1]*wb0[1] + ub0[2]*wb0[2] + ub0[3]*wb0[3]
        + ub1[0]*wb1[0] + ub1[1]*wb1[1] + ub1[2]*wb1[2] + ub1[3]*wb1[3];
    } else {
      bf16x8 z;
      #pragma unroll
      for (int j = 0; j < 8; ++j) z[j] = (__bf16)0.f;
      nt_store16(Hbp + (pA + row) * 64 + inner, z);
      nt_store16(Hbp + (pB + row) * 64 + inner, z);
      s = 0.f;
    }
    s += __shfl_xor(s, 1);
    s += __shfl_xor(s, 2);
    if ((l & 3) == 0) dvl[wv * 32 + i][l >> 2] = s;
  }
  *(f32x4*)(&deP[wv][l * 8])       = deA0;
  *(f32x4*)(&deP[wv][l * 8 + 4])   = deA1;
  *(f32x4*)(&deP[wv][512 + l * 8])     = deB0;
  *(f32x4*)(&deP[wv][512 + l * 8 + 4]) = deB1;
  __syncthreads();
  if (t < 128) {
    float s = 0.f;
    #pragma unroll
    for (int j = 0; j < 16; ++j) s += dvl[t][j];
    Dvp[(long)vbx * NNP + n0 + t] = s;
  }
  {
    float s0 = deP[0][t] + deP[1][t] + deP[2][t] + deP[3][t];
    float s1 = deP[0][512 + t] + deP[1][512 + t] + deP[2][512 + t] + deP[3][512 + t];
    float s2 = deP[0][256 + t] + deP[1][256 + t] + deP[2][256 + t] + deP[3][256 + t];
    float s3 = deP[0][768 + t] + deP[1][768 + t] + deP[2][768 + t] + deP[3][768 + t];
    Dep[(long)vby * NE + e0 + t] = s0;
    Dep[(long)vby * NE + e0 + 256 + t] = s2;
    Dep[(long)vby * NE + e0 + 512 + t] = s1;
    Dep[(long)vby * NE + e0 + 768 + t] = s3;
  }
}

// ---------------- cat GEMM body (f32 A, 32 rows x 128 cols per block) ------
__device__ __forceinline__ void cat_gemm_body(const float* __restrict__ Av, int lda,
    const bf16_t* __restrict__ Bt, int K, const float* __restrict__ bias,
    bf16_t* __restrict__ dst, int vbx) {
  int tid = threadIdx.x, l = tid & 63, wv = tid >> 6;
  int lr = l & 15, lq = l >> 4;
  int mo = vbx * 32 + (wv >> 1) * 16;
  int no = (wv & 1) * 64;
  f32x4 acc[4] = {};
  for (int k0 = 0; k0 < K; k0 += 32) {
    int row = mo + lr;
    bf16x8 a;
    if (row < NN) {
      const float* ap = Av + (long)row * lda + k0 + lq * 8;
      f32x4 u0 = *(const f32x4*)ap, u1 = *(const f32x4*)(ap + 4);
      #pragma unroll
      for (int j = 0; j < 4; ++j) { a[j] = (__bf16)u0[j]; a[j + 4] = (__bf16)u1[j]; }
    } else {
      #pragma unroll
      for (int j = 0; j < 8; ++j) a[j] = (__bf16)0.f;
    }
    #pragma unroll
    for (int ni = 0; ni < 4; ++ni) {
      bf16x8 b = *(const bf16x8*)(Bt + (long)(no + ni * 16 + lr) * K + k0 + lq * 8);
      acc[ni] = mfma16(a, b, acc[ni]);
    }
  }
  #pragma unroll
  for (int ni = 0; ni < 4; ++ni) {
    int colf = no + ni * 16 + lr;
    int rb = mo + lq * 4;
    float bs = bias[colf];
    #pragma unroll
    for (int r = 0; r < 4; ++r) {
      int n = rb + r;
      if (n < NN) dst[(long)n * 256 + colf] = (__bf16)(acc[ni][r] + bs);
    }
  }
}

// ---- fusedA: blocks [0,640) stats, [640,1265) psi, [1265,1890) phi --------
__global__ __launch_bounds__(256) void fusedA_kern(const float* __restrict__ H,
    const float* __restrict__ w, float* __restrict__ Dvp, float* __restrict__ Dep,
    bf16_t* __restrict__ Hbp,
    const float* __restrict__ x, const bf16_t* __restrict__ psi_wt,
    const float* __restrict__ psi_b,
    const float* __restrict__ z, const bf16_t* __restrict__ phi_wt,
    const float* __restrict__ phi_b, bf16_t* __restrict__ cat) {
  __shared__ float dvl[128][17];
  __shared__ float deP[4][1024];
  int bid = blockIdx.x;
  if (bid < 640) {
    stats_body(bid & 3, bid >> 2, H, w, Dvp, Dep, Hbp, dvl, deP);
  } else if (bid < 1265) {
    cat_gemm_body(x, 512, psi_wt, 512, psi_b, cat, bid - 640);
  } else {
    cat_gemm_body(z, 256, phi_wt, 256, phi_b, cat + 128, bid - 1265);
  }
}

// ---- fusedB: blocks [0,79) finalize, [79,1329) g1 relu GEMM ---------------
__global__ __launch_bounds__(256) void fusedB_kern(const float* __restrict__ Dvp,
    const float* __restrict__ Dep, const float* __restrict__ w,
    float* __restrict__ isd, float* __restrict__ es,
    const bf16_t* __restrict__ cat, const bf16_t* __restrict__ g1w,
    const float* __restrict__ g1b, bf16_t* __restrict__ hid1) {
  int bid = blockIdx.x;
  if (bid < 79) {
    int t = bid * 256 + threadIdx.x;
    if (t < NN) {
      float s = 0.f;
      #pragma unroll
      for (int b = 0; b < NEB; ++b) s += Dvp[(long)b * NNP + t];
      isd[t] = rsqrtf(fmaxf(s, 1e-6f));
    }
    if (t < NE) {
      float s = 0.f;
      #pragma unroll 8
      for (int b = 0; b < NNB; ++b) s += Dep[(long)b * NE + t];
      es[t] = w[t] / fmaxf(s, 1e-6f);
    }
    return;
  }
  int i = bid - 79;
  int vbx = i % 625, vby = i / 625;
  int tid = threadIdx.x, l = tid & 63, wv = tid >> 6;
  int lr = l & 15, lq = l >> 4;
  int mo = vbx * 32 + (wv >> 1) * 16;
  int no = vby * 128 + (wv & 1) * 64;
  f32x4 acc[4] = {};
  for (int k0 = 0; k0 < 256; k0 += 32) {
    int row = mo + lr;
    bf16x8 a;
    if (row < NN) {
      a = *(const bf16x8*)(cat + (long)row * 256 + k0 + lq * 8);
    } else {
      #pragma unroll
      for (int j = 0; j < 8; ++j) a[j] = (__bf16)0.f;
    }
    #pragma unroll
    for (int ni = 0; ni < 4; ++ni) {
      bf16x8 b = *(const bf16x8*)(g1w + (long)(no + ni * 16 + lr) * 256 + k0 + lq * 8);
      acc[ni] = mfma16(a, b, acc[ni]);
    }
  }
  #pragma unroll
  for (int ni = 0; ni < 4; ++ni) {
    int colf = no + ni * 16 + lr;
    int rb = mo + lq * 4;
    float bs = g1b[colf];
    #pragma unroll
    for (int r = 0; r < 4; ++r) {
      int n = rb + r;
      if (n < NN) {
        float xx = acc[ni][r] + bs;
        hid1[(long)n * 256 + colf] = (__bf16)(xx > 0.f ? xx : 0.f);
      }
    }
  }
}

// -------------------------------------------- weight transpose+cast (tiny)
__global__ void cvtw_kern(const float* __restrict__ psi, const float* __restrict__ phi,
                          const float* __restrict__ g1,  const float* __restrict__ g2,
                          const float* __restrict__ th1, const float* __restrict__ th2,
                          bf16_t* dpsi, bf16_t* dphi, bf16_t* dg1, bf16_t* dg2,
                          bf16_t* dth1, bf16_t* dth2) {
  int t = blockIdx.x * 256 + threadIdx.x;
  if (t < 65536) {
    int nc = t >> 9, k = t & 511; dpsi[t] = (__bf16)psi[k * 128 + nc];
  } else if (t < 98304) {
    int i = t - 65536; int nc = i >> 8, k = i & 255; dphi[i] = (__bf16)phi[k * 128 + nc];
  } else if (t < 163840) {
    int i = t - 98304; int nc = i >> 8, k = i & 255; dg1[i] = (__bf16)g1[k * 256 + nc];
  } else if (t < 196608) {
    int i = t - 163840; int nc = i >> 8, k = i & 255; dg2[i] = (__bf16)g2[k * 128 + nc];
  } else if (t < 229376) {
    int i = t - 196608; int nc = i >> 7, k = i & 127; dth1[i] = (__bf16)th1[k * 256 + nc];
  } else if (t < 294912) {
    int i = t - 229376; int nc = i >> 8, k = i & 255; dth2[i] = (__bf16)th2[k * 256 + nc];
  }
}

// ------------- fused gate + fused-features + Y1 = fused@th1*isd -----------
__global__ __launch_bounds__(256) void gate_y_kern(
    const bf16_t* __restrict__ hid1, const bf16_t* __restrict__ g2w,
    const float* __restrict__ g2b, const bf16_t* __restrict__ cat,
    const bf16_t* __restrict__ th1w, const float* __restrict__ isd,
    float* __restrict__ gate_out, bf16_t* __restrict__ Yf) {
  __shared__ bf16_t fl[32 * 132];     // fused tile, stride 132 bf16
  int t = threadIdx.x, l = t & 63, wv = t >> 6;
  int lr = l & 15, lq = l >> 4;
  if (blockIdx.x >= 625) {            // pad nblk: zero fragments
    bf16x8 z;
    #pragma unroll
    for (int j = 0; j < 8; ++j) z[j] = (__bf16)0.f;
    #pragma unroll
    for (int i = 0; i < 4; ++i)
      *(bf16x8*)(Yf + (((long)(wv + i * 4) * 640 + blockIdx.x) * 64 + l) * 8) = z;
    return;
  }
  long n0 = (long)blockIdx.x * 32;
  int hm = wv >> 1, nq = wv & 1;
  int mo = hm * 16, no = nq * 64;
  f32x4 acc[4] = {};
  for (int k0 = 0; k0 < 256; k0 += 32) {
    bf16x8 a = *(const bf16x8*)(hid1 + (n0 + mo + lr) * 256 + k0 + lq * 8);
    #pragma unroll
    for (int ni = 0; ni < 4; ++ni) {
      bf16x8 b = *(const bf16x8*)(g2w + (long)(no + ni * 16 + lr) * 256 + k0 + lq * 8);
      acc[ni] = mfma16(a, b, acc[ni]);
    }
  }
  #pragma unroll
  for (int ni = 0; ni < 4; ++ni) {
    int colf = no + ni * 16 + lr;
    float bs = g2b[colf];
    #pragma unroll
    for (int r = 0; r < 4; ++r) {
      long n = n0 + mo + lq * 4 + r;
      float g = 1.f / (1.f + __expf(-(acc[ni][r] + bs)));
      gate_out[n * 128 + colf] = g;
      float px = (float)cat[n * 256 + colf];
      float pz = (float)cat[n * 256 + 128 + colf];
      fl[(mo + lq * 4 + r) * 132 + colf] = (__bf16)(g * pz + (1.f - g) * px);
    }
  }
  __syncthreads();
  int hm2 = wv >> 1, f128 = (wv & 1) * 128;
  f32x4 acc2[8] = {};
  for (int k0 = 0; k0 < 128; k0 += 32) {
    bf16x8 a = *(const bf16x8*)(fl + (hm2 * 16 + lr) * 132 + k0 + lq * 8);
    #pragma unroll
    for (int ni = 0; ni < 8; ++ni) {
      bf16x8 b = *(const bf16x8*)(th1w + (long)(f128 + ni * 16 + lr) * 128 + k0 + lq * 8);
      acc2[ni] = mfma16(a, b, acc2[ni]);
    }
  }
  int lanep = (hm2 * 2 + (lq >> 1)) * 16 + lr;
  #pragma unroll
  for (int ni = 0; ni < 8; ++ni) {
    int fblk = (f128 >> 4) + ni;
    bf16x4 pk;
    #pragma unroll
    for (int r = 0; r < 4; ++r) {
      long n = n0 + hm2 * 16 + lq * 4 + r;
      pk[r] = (__bf16)(acc2[ni][r] * isd[n]);
    }
    *(bf16x4*)(Yf + (((long)fblk * 640 + blockIdx.x) * 64 + lanep) * 8 + (lq & 1) * 4) = pk;
  }
}

// --------------------------------------------- He partials: fragment-major
// Double-buffered LDS transpose tile, ONE barrier per 64-row step.
// Hbp loads + part stores nontemporal (single-use streams).
__global__ __launch_bounds__(512) void at_gemm_kern(const bf16_t* __restrict__ Hbp,
                                                    const bf16_t* __restrict__ Yf,
                                                    bf16_t* __restrict__ part) {
  __shared__ bf16_t T[2][128 * 72];    // [buf][e_local][64 n + pad]
  int t = threadIdx.x, l = t & 63, wv = t >> 6;
  int lr = l & 15, lq = l >> 4;
  int eh = wv >> 2, fq = wv & 3;
  int e0 = blockIdx.x * 128;
  int s0 = blockIdx.y * 20;
  int rp = t >> 4;
  int ck = t & 15;
  f32x4 acc[4][4] = {};
  const bf16_t* src = Hbp + (((long)(e0 >> 6) + (ck >> 3)) * NNP + (long)s0 * 64 + 2 * rp) * 64
                          + (ck & 7) * 8;
  bf16x8 ra = nt_load16(src);
  bf16x8 rb = nt_load16(src + 64);
  {
    #pragma unroll
    for (int j = 0; j < 8; ++j) {
      int jj = (j + ck) & 7;
      int el = ck * 8 + jj;
      unsigned lo = (unsigned)__builtin_bit_cast(unsigned short, (__bf16)ra[jj]);
      unsigned hi = (unsigned)__builtin_bit_cast(unsigned short, (__bf16)rb[jj]);
      *(unsigned*)(&T[0][el * 72 + rp * 2]) = lo | (hi << 16);
    }
    src += 64 * 64;
    ra = nt_load16(src);
    rb = nt_load16(src + 64);
  }
  for (int i = 0; i < 20; ++i) {
    __syncthreads();
    if (i + 1 < 20) {
      int nb = (i + 1) & 1;
      #pragma unroll
      for (int j = 0; j < 8; ++j) {
        int jj = (j + ck) & 7;
        int el = ck * 8 + jj;
        unsigned lo = (unsigned)__builtin_bit_cast(unsigned short, (__bf16)ra[jj]);
        unsigned hi = (unsigned)__builtin_bit_cast(unsigned short, (__bf16)rb[jj]);
        *(unsigned*)(&T[nb][el * 72 + rp * 2]) = lo | (hi << 16);
      }
    }
    if (i + 2 < 20) {
      src += 64 * 64;
      ra = nt_load16(src);
      rb = nt_load16(src + 64);
    }
    int cb = i & 1;
    int s = s0 + i;
    #pragma unroll
    for (int k32 = 0; k32 < 2; ++k32) {
      bf16x8 a[4], b[4];
      #pragma unroll
      for (int ni = 0; ni < 4; ++ni)
        a[ni] = *(const bf16x8*)(&T[cb][(eh * 64 + ni * 16 + lr) * 72 + k32 * 32 + lq * 8]);
      const bf16_t* bp = Yf + ((long)(s * 2 + k32) * 64 + l) * 8;
      #pragma unroll
      for (int ni = 0; ni < 4; ++ni)
        b[ni] = *(const bf16x8*)(bp + (long)(fq * 4 + ni) * 640 * 512);
      #pragma unroll
      for (int ae = 0; ae < 4; ++ae)
        #pragma unroll
        for (int bf = 0; bf < 4; ++bf)
          acc[ae][bf] = mfma16(a[ae], b[bf], acc[ae][bf]);
    }
  }
  bf16_t* pp = part + (long)blockIdx.y * (256 * 4096);
  #pragma unroll
  for (int ae = 0; ae < 4; ++ae) {
    int eblk16 = (e0 >> 4) + eh * 4 + ae;
    #pragma unroll
    for (int bf = 0; bf < 4; ++bf) {
      int fblk = fq * 4 + bf;
      f32x4 v = acc[ae][bf];
      bf16x4 pk;
      for (int r = 0; r < 4; ++r) pk[r] = (__bf16)v[r];
      nt_store8(pp + (((long)eblk16 * 16 + fblk) * 64 + l) * 4, pk);
    }
  }
}

// Hef[f][e] (fragment-major) = es[e] * sum_s part[s][...]
__global__ __launch_bounds__(256) void reduce_he(const bf16_t* __restrict__ part,
                                                 const float* __restrict__ es,
                                                 bf16_t* __restrict__ Hef) {
  int u = blockIdx.x * 256 + threadIdx.x;
  int lane = u & 63, tile = u >> 6;
  int fblk = tile & 15, eblk16 = tile >> 4;
  int lr = lane & 15, lq = lane >> 4;
  int e_base = eblk16 * 16 + lq * 4;
  float a0 = 0.f, a1 = 0.f, a2 = 0.f, a3 = 0.f;
  #pragma unroll
  for (int s = 0; s < AT_S; ++s) {
    bf16x4 v = nt_load8(part + (long)s * (256 * 4096) + (long)u * 4);
    a0 += (float)v[0]; a1 += (float)v[1]; a2 += (float)v[2]; a3 += (float)v[3];
  }
  f32x4 e4 = *(const f32x4*)(es + e_base);
  bf16x4 pk;
  pk[0] = (__bf16)(a0 * e4[0]); pk[1] = (__bf16)(a1 * e4[1]);
  pk[2] = (__bf16)(a2 * e4[2]); pk[3] = (__bf16)(a3 * e4[3]);
  int eblk32 = eblk16 >> 1;
  int lanep = ((eblk16 & 1) * 2 + (lq >> 1)) * 16 + lr;
  long slot = (((long)fblk * 128 + eblk32) * 64 + lanep) * 8 + (lq & 1) * 4;
  *(bf16x4*)(Hef + slot) = pk;
}

// -------- conv out: 256 blocks x 80 rows, 8 waves, perfect CU balance -----
// CONV=1: fuse Y2 = h@th2*isd (h stays in LDS). CONV=2: fuse logits.
// Hbp streaming loads nontemporal.
template<int CONV>
__global__ __launch_bounds__(512) void out_gemm_kern(const bf16_t* __restrict__ Hef,
                                                     const bf16_t* __restrict__ Hbp,
                                                     const float* __restrict__ isd,
                                                     const float* __restrict__ bias,
                                                     const bf16_t* __restrict__ th2w,
                                                     bf16_t* __restrict__ Yf,
                                                     const float* __restrict__ ow,
                                                     const float* __restrict__ ob,
                                                     float* __restrict__ out) {
  __shared__ bf16_t lbuf[2][5120];     // [buf][frag 10][lane 64][8]
  __shared__ float lgp[8][80][2];      // CONV2 logits partials
  __shared__ bf16_t hl[80 * 260];      // CONV1 h tile, stride 260 bf16
  int t = threadIdx.x, l = t & 63, wv = t >> 6;
  int lr = l & 15, lq = l >> 4;
  long r0 = (long)blockIdx.x * 80;
  f32x4 acc[5][2] = {};
  int f1 = wv, f2 = 8 + wv;
  bool has2 = wv < 2;
  const bf16_t* asrc1 = Hbp + (r0 + (f1 >> 1) * 16 + lr) * 64 + (f1 & 1) * 32 + lq * 8;
  const bf16_t* asrc2 = Hbp + (r0 + (f2 >> 1) * 16 + lr) * 64 + (f2 & 1) * 32 + lq * 8;
  const bf16_t* bbase = Hef + (long)l * 8;
  bf16x8 rg1 = nt_load16(asrc1);
  bf16x8 rg2;
  if (has2) rg2 = nt_load16(asrc2);
  int c = 0;
  for (int s = 0; s < 64; ++s) {
    *(bf16x8*)(&lbuf[c][f1 * 512 + l * 8]) = rg1;
    if (has2) *(bf16x8*)(&lbuf[c][f2 * 512 + l * 8]) = rg2;
    __syncthreads();
    if (s + 1 < 64) {
      rg1 = nt_load16(asrc1 + (long)(s + 1) * NNP * 64);
      if (has2) rg2 = nt_load16(asrc2 + (long)(s + 1) * NNP * 64);
    }
    #pragma unroll
    for (int k32 = 0; k32 < 2; ++k32) {
      bf16x8 a[5], b[2];
      #pragma unroll
      for (int mi = 0; mi < 5; ++mi)
        a[mi] = *(const bf16x8*)(&lbuf[c][(mi * 2 + k32) * 512 + l * 8]);
      int eblk = s * 2 + k32;
      #pragma unroll
      for (int ni = 0; ni < 2; ++ni)
        b[ni] = *(const bf16x8*)(bbase + ((long)(wv * 2 + ni) * 128 + eblk) * 512);
      #pragma unroll
      for (int mi = 0; mi < 5; ++mi) {
        acc[mi][0] = mfma16(a[mi], b[0], acc[mi][0]);
        acc[mi][1] = mfma16(a[mi], b[1], acc[mi][1]);
      }
    }
    c ^= 1;
  }
  #pragma unroll
  for (int mi = 0; mi < 5; ++mi) {
    long nb = r0 + mi * 16 + lq * 4;
    #pragma unroll
    for (int r = 0; r < 4; ++r) {
      long n = nb + r;
      float sd = (n < NN) ? isd[n] : 0.f;
      float a0 = 0.f, a1 = 0.f;
      #pragma unroll
      for (int ni = 0; ni < 2; ++ni) {
        int f = wv * 32 + ni * 16 + lr;
        float vv = acc[mi][ni][r] * sd + bias[f];
        vv = vv > 0.f ? vv : 0.f;
        if constexpr (CONV == 1) {
          hl[(mi * 16 + lq * 4 + r) * 260 + f] = (__bf16)vv;
        } else {
          a0 += vv * ow[f * 2];
          a1 += vv * ow[f * 2 + 1];
        }
      }
      if constexpr (CONV == 2) {
        #pragma unroll
        for (int m = 1; m < 16; m <<= 1) { a0 += __shfl_xor(a0, m); a1 += __shfl_xor(a1, m); }
        if (lr == 0) {
          int rowl = mi * 16 + lq * 4 + r;
          lgp[wv][rowl][0] = a0;
          lgp[wv][rowl][1] = a1;
        }
      }
    }
  }
  if constexpr (CONV == 1) {
    __syncthreads();
    f32x4 acc2[5][2] = {};
    for (int k0 = 0; k0 < 256; k0 += 32) {
      bf16x8 a_[5], b2[2];
      #pragma unroll
      for (int mi = 0; mi < 5; ++mi)
        a_[mi] = *(const bf16x8*)(hl + (mi * 16 + lr) * 260 + k0 + lq * 8);
      #pragma unroll
      for (int ni = 0; ni < 2; ++ni)
        b2[ni] = *(const bf16x8*)(th2w + (long)(wv * 32 + ni * 16 + lr) * 256 + k0 + lq * 8);
      #pragma unroll
      for (int mi = 0; mi < 5; ++mi) {
        acc2[mi][0] = mfma16(a_[mi], b2[0], acc2[mi][0]);
        acc2[mi][1] = mfma16(a_[mi], b2[1], acc2[mi][1]);
      }
    }
    #pragma unroll
    for (int mi = 0; mi < 5; ++mi) {
      long nbase = r0 + mi * 16;
      long nblk = nbase >> 5;
      int hm16 = (int)((nbase >> 4) & 1);
      int lanep = (hm16 * 2 + (lq >> 1)) * 16 + lr;
      #pragma unroll
      for (int ni = 0; ni < 2; ++ni) {
        int fblk = wv * 2 + ni;
        bf16x4 pk;
        #pragma unroll
        for (int r = 0; r < 4; ++r) {
          long n = nbase + lq * 4 + r;
          float sc = (n < NN) ? isd[n] : 0.f;
          pk[r] = (__bf16)(acc2[mi][ni][r] * sc);
        }
        *(bf16x4*)(Yf + (((long)fblk * 640 + nblk) * 64 + lanep) * 8 + (lq & 1) * 4) = pk;
      }
    }
  } else {
    __syncthreads();
    if (t < 80) {
      float s0 = 0.f, s1 = 0.f;
      #pragma unroll
      for (int wvi = 0; wvi < 8; ++wvi) { s0 += lgp[wvi][t][0]; s1 += lgp[wvi][t][1]; }
      long n = r0 + t;
      if (n < NN) {
        out[n * 2]     = s0 + ob[0];
        out[n * 2 + 1] = s1 + ob[1];
      }
    }
  }
}

// ============================================================== launcher
extern "C" void kernel_launch(void* const* d_in, const int* in_sizes, int n_in,
                              void* d_out, int out_size, void* d_ws, size_t ws_size,
                              hipStream_t stream) {
  const float* x    = (const float*)d_in[0];
  const float* z    = (const float*)d_in[1];
  const float* H    = (const float*)d_in[2];
  const float* w    = (const float*)d_in[3];
  const float* psi_w = (const float*)d_in[4];
  const float* psi_b = (const float*)d_in[5];
  const float* phi_w = (const float*)d_in[6];
  const float* phi_b = (const float*)d_in[7];
  const float* g1_w  = (const float*)d_in[8];
  const float* g1_b  = (const float*)d_in[9];
  const float* g2_w  = (const float*)d_in[10];
  const float* g2_b  = (const float*)d_in[11];
  const float* th1   = (const float*)d_in[12];
  const float* b1    = (const float*)d_in[13];
  const float* th2   = (const float*)d_in[14];
  const float* b2    = (const float*)d_in[15];
  const float* out_w = (const float*)d_in[16];
  const float* out_b = (const float*)d_in[17];

  float* logits_out = (float*)d_out;                 // [20000][2]
  float* gate_out   = logits_out + (size_t)NN * 2;   // [20000][128]

  char* p = (char*)d_ws;
  auto alloc = [&](size_t bytes) { char* r = p; p += (bytes + 255) & ~(size_t)255; return r; };
  float* Dvp  = (float*)alloc((size_t)NEB * NNP * 4);
  float* Dep  = (float*)alloc((size_t)NNB * NE * 4);
  float* isd  = (float*)alloc((size_t)NN * 4);
  float* es   = (float*)alloc((size_t)NE * 4);
  bf16_t* cat   = (bf16_t*)alloc((size_t)NN * 256 * 2);
  bf16_t* hid1  = (bf16_t*)alloc((size_t)NN * 256 * 2);
  bf16_t* Yf    = (bf16_t*)alloc((size_t)16 * 640 * 512 * 2);   // 10.49 MB
  bf16_t* Hef   = (bf16_t*)alloc((size_t)16 * 128 * 512 * 2);   // 2.1 MB
  bf16_t* pbuf  = (bf16_t*)alloc((size_t)AT_S * 256 * 4096 * 2); // 33.5 MB
  bf16_t* Hbp   = (bf16_t*)alloc((size_t)NNP * NE * 2);          // 168 MB
  bf16_t* psi_wt = (bf16_t*)alloc(65536 * 2);
  bf16_t* phi_wt = (bf16_t*)alloc(32768 * 2);
  bf16_t* g1_wt  = (bf16_t*)alloc(65536 * 2);
  bf16_t* g2_wt  = (bf16_t*)alloc(32768 * 2);
  bf16_t* th1_wt = (bf16_t*)alloc(32768 * 2);
  bf16_t* th2_wt = (bf16_t*)alloc(65536 * 2);

  cvtw_kern<<<1152, 256, 0, stream>>>(psi_w, phi_w, g1_w, g2_w, th1, th2,
                                      psi_wt, phi_wt, g1_wt, g2_wt, th1_wt, th2_wt);
  // stats + psi + phi overlapped in one launch
  fusedA_kern<<<1890, 256, 0, stream>>>(H, w, Dvp, Dep, Hbp,
                                        x, psi_wt, psi_b, z, phi_wt, phi_b, cat);
  // finalize + g1 overlapped in one launch
  fusedB_kern<<<1329, 256, 0, stream>>>(Dvp, Dep, w, isd, es,
                                        cat, g1_wt, g1_b, hid1);
  gate_y_kern<<<640, 256, 0, stream>>>(hid1, g2_wt, g2_b, cat, th1_wt, isd, gate_out, Yf);

  // hconv 1 (+ fused Y2 producer)
  at_gemm_kern<<<dim3(32, AT_S), 512, 0, stream>>>(Hbp, Yf, pbuf);
  reduce_he<<<1024, 256, 0, stream>>>(pbuf, es, Hef);
  out_gemm_kern<1><<<256, 512, 0, stream>>>(Hef, Hbp, isd, b1, th2_wt, Yf,
                                            nullptr, nullptr, nullptr);

  // hconv 2 (+ fused logits)
  at_gemm_kern<<<dim3(32, AT_S), 512, 0, stream>>>(Hbp, Yf, pbuf);
  reduce_he<<<1024, 256, 0, stream>>>(pbuf, es, Hef);
  out_gemm_kern<2><<<256, 512, 0, stream>>>(Hef, Hbp, isd, b2, nullptr, nullptr,
                                            out_w, out_b, logits_out);

  (void)in_sizes; (void)n_in; (void)out_size; (void)ws_size;
}

// Round 18
// 495.179 us; speedup vs baseline: 1.0992x; 1.0992x over previous
//
#include <hip/hip_runtime.h>
#include <hip/hip_bf16.h>

// DF-HGNN fused pipeline v18 = v16 (best measured, 495.8us): revert of v17's
// nontemporal-hint regression. Final configuration.
//  - fusedA = stats (4x160, 1024-col blocks, 4-deep load ILP) + psi + phi.
//  - fusedB = finalize + g1. gate_y fuses gate+fused+Y1. at_gemm dbuf LDS.
//  - out_gemm 256x80 balanced, CONV1 fuses Y2, CONV2 fuses logits.
// N=20000, E=4096, IN=512, DET=256, HID=256, HALF=128, OUT=2.

typedef __bf16 bf16_t;
typedef __attribute__((ext_vector_type(8))) __bf16 bf16x8;
typedef __attribute__((ext_vector_type(4))) __bf16 bf16x4;
typedef __attribute__((ext_vector_type(4))) float f32x4;

#define NN 20000
#define NE 4096
#define NNP 20480           // 640*32 padded node extent
#define AT_S 16             // n-split for H^T @ Y
#define NEB 4               // e-blocks in stats grid (1024 cols each)
#define NNB 160             // n-blocks in stats grid (128 rows each)
// Layouts:
//  Hbp [p=e>>6][n][e&63]               : column-panel-tiled bf16 H
//  Yf  [fblk 16][nblk 640][lane 64][8] : value(f,n) at lane=((n&31)>>3)*16+(f&15), j=n&7
//  Hef [fblk 16][eblk 128][lane 64][8] : value(f,e) same scheme with k=e
//  part[s][tile=eblk16*16+fblk][lane 64][4]

__device__ __forceinline__ f32x4 mfma16(bf16x8 a, bf16x8 b, f32x4 c) {
  return __builtin_amdgcn_mfma_f32_16x16x32_bf16(a, b, c, 0, 0, 0);
}

// ---------------- stats body (vbx 0..3 x 1024 cols, vby 0..159 x 128 rows) -
// Lane l owns cols e0+8l..+7 (half A) and e0+512+8l..+7 (half B):
// 4 independent f32x4 loads + 2 bf16x8 stores per row per thread.
__device__ __forceinline__ void stats_body(int vbx, int vby,
    const float* __restrict__ H, const float* __restrict__ w,
    float* __restrict__ Dvp, float* __restrict__ Dep, bf16_t* __restrict__ Hbp,
    float (*dvl)[17], float (*deP)[1024]) {
  int t = threadIdx.x, l = t & 63, wv = t >> 6;
  long e0 = (long)vbx * 1024;
  long n0 = (long)vby * 128;
  long pA = ((e0 >> 6) + (l >> 3)) * (long)NNP;
  long pB = (((e0 + 512) >> 6) + (l >> 3)) * (long)NNP;
  int inner = (l & 7) * 8;
  f32x4 wa0 = *(const f32x4*)(w + e0 + l * 8);
  f32x4 wa1 = *(const f32x4*)(w + e0 + l * 8 + 4);
  f32x4 wb0 = *(const f32x4*)(w + e0 + 512 + l * 8);
  f32x4 wb1 = *(const f32x4*)(w + e0 + 512 + l * 8 + 4);
  f32x4 deA0, deA1, deB0, deB1;
  deA0 = deA1 = deB0 = deB1 = f32x4{0.f, 0.f, 0.f, 0.f};
  const float* ha = H + e0 + l * 8;
  const float* hb = H + e0 + 512 + l * 8;
  #pragma unroll 4
  for (int i = 0; i < 32; ++i) {
    long row = n0 + wv * 32 + i;
    float s;
    if (row < NN) {
      f32x4 ua0 = *(const f32x4*)(ha + row * NE);
      f32x4 ua1 = *(const f32x4*)(ha + row * NE + 4);
      f32x4 ub0 = *(const f32x4*)(hb + row * NE);
      f32x4 ub1 = *(const f32x4*)(hb + row * NE + 4);
      bf16x8 pa, pb;
      #pragma unroll
      for (int j = 0; j < 4; ++j) {
        pa[j] = (__bf16)ua0[j]; pa[4 + j] = (__bf16)ua1[j];
        pb[j] = (__bf16)ub0[j]; pb[4 + j] = (__bf16)ub1[j];
      }
      *(bf16x8*)(Hbp + (pA + row) * 64 + inner) = pa;
      *(bf16x8*)(Hbp + (pB + row) * 64 + inner) = pb;
      deA0 += ua0; deA1 += ua1; deB0 += ub0; deB1 += ub1;
      s = ua0[0]*wa0[0] + ua0[1]*wa0[1] + ua0[2]*wa0[2] + ua0[3]*wa0[3]
        + ua1[0]*wa1[0] + ua1[1]*wa1[1] + ua1[2]*wa1[2] + ua1[3]*wa1[3]
        + ub0[0]*wb0[0] + ub0[1]*wb0[1] + ub0[2]*wb0[2] + ub0[3]*wb0[3]
        + ub1[0]*wb1[0] + ub1[1]*wb1[1] + ub1[2]*wb1[2] + ub1[3]*wb1[3];
    } else {
      bf16x8 z;
      #pragma unroll
      for (int j = 0; j < 8; ++j) z[j] = (__bf16)0.f;
      *(bf16x8*)(Hbp + (pA + row) * 64 + inner) = z;
      *(bf16x8*)(Hbp + (pB + row) * 64 + inner) = z;
      s = 0.f;
    }
    s += __shfl_xor(s, 1);
    s += __shfl_xor(s, 2);
    if ((l & 3) == 0) dvl[wv * 32 + i][l >> 2] = s;
  }
  *(f32x4*)(&deP[wv][l * 8])       = deA0;
  *(f32x4*)(&deP[wv][l * 8 + 4])   = deA1;
  *(f32x4*)(&deP[wv][512 + l * 8])     = deB0;
  *(f32x4*)(&deP[wv][512 + l * 8 + 4]) = deB1;
  __syncthreads();
  if (t < 128) {
    float s = 0.f;
    #pragma unroll
    for (int j = 0; j < 16; ++j) s += dvl[t][j];
    Dvp[(long)vbx * NNP + n0 + t] = s;
  }
  {
    float s0 = deP[0][t] + deP[1][t] + deP[2][t] + deP[3][t];
    float s1 = deP[0][512 + t] + deP[1][512 + t] + deP[2][512 + t] + deP[3][512 + t];
    float s2 = deP[0][256 + t] + deP[1][256 + t] + deP[2][256 + t] + deP[3][256 + t];
    float s3 = deP[0][768 + t] + deP[1][768 + t] + deP[2][768 + t] + deP[3][768 + t];
    Dep[(long)vby * NE + e0 + t] = s0;
    Dep[(long)vby * NE + e0 + 256 + t] = s2;
    Dep[(long)vby * NE + e0 + 512 + t] = s1;
    Dep[(long)vby * NE + e0 + 768 + t] = s3;
  }
}

// ---------------- cat GEMM body (f32 A, 32 rows x 128 cols per block) ------
__device__ __forceinline__ void cat_gemm_body(const float* __restrict__ Av, int lda,
    const bf16_t* __restrict__ Bt, int K, const float* __restrict__ bias,
    bf16_t* __restrict__ dst, int vbx) {
  int tid = threadIdx.x, l = tid & 63, wv = tid >> 6;
  int lr = l & 15, lq = l >> 4;
  int mo = vbx * 32 + (wv >> 1) * 16;
  int no = (wv & 1) * 64;
  f32x4 acc[4] = {};
  for (int k0 = 0; k0 < K; k0 += 32) {
    int row = mo + lr;
    bf16x8 a;
    if (row < NN) {
      const float* ap = Av + (long)row * lda + k0 + lq * 8;
      f32x4 u0 = *(const f32x4*)ap, u1 = *(const f32x4*)(ap + 4);
      #pragma unroll
      for (int j = 0; j < 4; ++j) { a[j] = (__bf16)u0[j]; a[j + 4] = (__bf16)u1[j]; }
    } else {
      #pragma unroll
      for (int j = 0; j < 8; ++j) a[j] = (__bf16)0.f;
    }
    #pragma unroll
    for (int ni = 0; ni < 4; ++ni) {
      bf16x8 b = *(const bf16x8*)(Bt + (long)(no + ni * 16 + lr) * K + k0 + lq * 8);
      acc[ni] = mfma16(a, b, acc[ni]);
    }
  }
  #pragma unroll
  for (int ni = 0; ni < 4; ++ni) {
    int colf = no + ni * 16 + lr;
    int rb = mo + lq * 4;
    float bs = bias[colf];
    #pragma unroll
    for (int r = 0; r < 4; ++r) {
      int n = rb + r;
      if (n < NN) dst[(long)n * 256 + colf] = (__bf16)(acc[ni][r] + bs);
    }
  }
}

// ---- fusedA: blocks [0,640) stats, [640,1265) psi, [1265,1890) phi --------
__global__ __launch_bounds__(256) void fusedA_kern(const float* __restrict__ H,
    const float* __restrict__ w, float* __restrict__ Dvp, float* __restrict__ Dep,
    bf16_t* __restrict__ Hbp,
    const float* __restrict__ x, const bf16_t* __restrict__ psi_wt,
    const float* __restrict__ psi_b,
    const float* __restrict__ z, const bf16_t* __restrict__ phi_wt,
    const float* __restrict__ phi_b, bf16_t* __restrict__ cat) {
  __shared__ float dvl[128][17];
  __shared__ float deP[4][1024];
  int bid = blockIdx.x;
  if (bid < 640) {
    stats_body(bid & 3, bid >> 2, H, w, Dvp, Dep, Hbp, dvl, deP);
  } else if (bid < 1265) {
    cat_gemm_body(x, 512, psi_wt, 512, psi_b, cat, bid - 640);
  } else {
    cat_gemm_body(z, 256, phi_wt, 256, phi_b, cat + 128, bid - 1265);
  }
}

// ---- fusedB: blocks [0,79) finalize, [79,1329) g1 relu GEMM ---------------
__global__ __launch_bounds__(256) void fusedB_kern(const float* __restrict__ Dvp,
    const float* __restrict__ Dep, const float* __restrict__ w,
    float* __restrict__ isd, float* __restrict__ es,
    const bf16_t* __restrict__ cat, const bf16_t* __restrict__ g1w,
    const float* __restrict__ g1b, bf16_t* __restrict__ hid1) {
  int bid = blockIdx.x;
  if (bid < 79) {
    int t = bid * 256 + threadIdx.x;
    if (t < NN) {
      float s = 0.f;
      #pragma unroll
      for (int b = 0; b < NEB; ++b) s += Dvp[(long)b * NNP + t];
      isd[t] = rsqrtf(fmaxf(s, 1e-6f));
    }
    if (t < NE) {
      float s = 0.f;
      #pragma unroll 8
      for (int b = 0; b < NNB; ++b) s += Dep[(long)b * NE + t];
      es[t] = w[t] / fmaxf(s, 1e-6f);
    }
    return;
  }
  int i = bid - 79;
  int vbx = i % 625, vby = i / 625;
  int tid = threadIdx.x, l = tid & 63, wv = tid >> 6;
  int lr = l & 15, lq = l >> 4;
  int mo = vbx * 32 + (wv >> 1) * 16;
  int no = vby * 128 + (wv & 1) * 64;
  f32x4 acc[4] = {};
  for (int k0 = 0; k0 < 256; k0 += 32) {
    int row = mo + lr;
    bf16x8 a;
    if (row < NN) {
      a = *(const bf16x8*)(cat + (long)row * 256 + k0 + lq * 8);
    } else {
      #pragma unroll
      for (int j = 0; j < 8; ++j) a[j] = (__bf16)0.f;
    }
    #pragma unroll
    for (int ni = 0; ni < 4; ++ni) {
      bf16x8 b = *(const bf16x8*)(g1w + (long)(no + ni * 16 + lr) * 256 + k0 + lq * 8);
      acc[ni] = mfma16(a, b, acc[ni]);
    }
  }
  #pragma unroll
  for (int ni = 0; ni < 4; ++ni) {
    int colf = no + ni * 16 + lr;
    int rb = mo + lq * 4;
    float bs = g1b[colf];
    #pragma unroll
    for (int r = 0; r < 4; ++r) {
      int n = rb + r;
      if (n < NN) {
        float xx = acc[ni][r] + bs;
        hid1[(long)n * 256 + colf] = (__bf16)(xx > 0.f ? xx : 0.f);
      }
    }
  }
}

// -------------------------------------------- weight transpose+cast (tiny)
__global__ void cvtw_kern(const float* __restrict__ psi, const float* __restrict__ phi,
                          const float* __restrict__ g1,  const float* __restrict__ g2,
                          const float* __restrict__ th1, const float* __restrict__ th2,
                          bf16_t* dpsi, bf16_t* dphi, bf16_t* dg1, bf16_t* dg2,
                          bf16_t* dth1, bf16_t* dth2) {
  int t = blockIdx.x * 256 + threadIdx.x;
  if (t < 65536) {
    int nc = t >> 9, k = t & 511; dpsi[t] = (__bf16)psi[k * 128 + nc];
  } else if (t < 98304) {
    int i = t - 65536; int nc = i >> 8, k = i & 255; dphi[i] = (__bf16)phi[k * 128 + nc];
  } else if (t < 163840) {
    int i = t - 98304; int nc = i >> 8, k = i & 255; dg1[i] = (__bf16)g1[k * 256 + nc];
  } else if (t < 196608) {
    int i = t - 163840; int nc = i >> 8, k = i & 255; dg2[i] = (__bf16)g2[k * 128 + nc];
  } else if (t < 229376) {
    int i = t - 196608; int nc = i >> 7, k = i & 127; dth1[i] = (__bf16)th1[k * 256 + nc];
  } else if (t < 294912) {
    int i = t - 229376; int nc = i >> 8, k = i & 255; dth2[i] = (__bf16)th2[k * 256 + nc];
  }
}

// ------------- fused gate + fused-features + Y1 = fused@th1*isd -----------
__global__ __launch_bounds__(256) void gate_y_kern(
    const bf16_t* __restrict__ hid1, const bf16_t* __restrict__ g2w,
    const float* __restrict__ g2b, const bf16_t* __restrict__ cat,
    const bf16_t* __restrict__ th1w, const float* __restrict__ isd,
    float* __restrict__ gate_out, bf16_t* __restrict__ Yf) {
  __shared__ bf16_t fl[32 * 132];     // fused tile, stride 132 bf16
  int t = threadIdx.x, l = t & 63, wv = t >> 6;
  int lr = l & 15, lq = l >> 4;
  if (blockIdx.x >= 625) {            // pad nblk: zero fragments
    bf16x8 z;
    #pragma unroll
    for (int j = 0; j < 8; ++j) z[j] = (__bf16)0.f;
    #pragma unroll
    for (int i = 0; i < 4; ++i)
      *(bf16x8*)(Yf + (((long)(wv + i * 4) * 640 + blockIdx.x) * 64 + l) * 8) = z;
    return;
  }
  long n0 = (long)blockIdx.x * 32;
  int hm = wv >> 1, nq = wv & 1;
  int mo = hm * 16, no = nq * 64;
  f32x4 acc[4] = {};
  for (int k0 = 0; k0 < 256; k0 += 32) {
    bf16x8 a = *(const bf16x8*)(hid1 + (n0 + mo + lr) * 256 + k0 + lq * 8);
    #pragma unroll
    for (int ni = 0; ni < 4; ++ni) {
      bf16x8 b = *(const bf16x8*)(g2w + (long)(no + ni * 16 + lr) * 256 + k0 + lq * 8);
      acc[ni] = mfma16(a, b, acc[ni]);
    }
  }
  #pragma unroll
  for (int ni = 0; ni < 4; ++ni) {
    int colf = no + ni * 16 + lr;
    float bs = g2b[colf];
    #pragma unroll
    for (int r = 0; r < 4; ++r) {
      long n = n0 + mo + lq * 4 + r;
      float g = 1.f / (1.f + __expf(-(acc[ni][r] + bs)));
      gate_out[n * 128 + colf] = g;
      float px = (float)cat[n * 256 + colf];
      float pz = (float)cat[n * 256 + 128 + colf];
      fl[(mo + lq * 4 + r) * 132 + colf] = (__bf16)(g * pz + (1.f - g) * px);
    }
  }
  __syncthreads();
  int hm2 = wv >> 1, f128 = (wv & 1) * 128;
  f32x4 acc2[8] = {};
  for (int k0 = 0; k0 < 128; k0 += 32) {
    bf16x8 a = *(const bf16x8*)(fl + (hm2 * 16 + lr) * 132 + k0 + lq * 8);
    #pragma unroll
    for (int ni = 0; ni < 8; ++ni) {
      bf16x8 b = *(const bf16x8*)(th1w + (long)(f128 + ni * 16 + lr) * 128 + k0 + lq * 8);
      acc2[ni] = mfma16(a, b, acc2[ni]);
    }
  }
  int lanep = (hm2 * 2 + (lq >> 1)) * 16 + lr;
  #pragma unroll
  for (int ni = 0; ni < 8; ++ni) {
    int fblk = (f128 >> 4) + ni;
    bf16x4 pk;
    #pragma unroll
    for (int r = 0; r < 4; ++r) {
      long n = n0 + hm2 * 16 + lq * 4 + r;
      pk[r] = (__bf16)(acc2[ni][r] * isd[n]);
    }
    *(bf16x4*)(Yf + (((long)fblk * 640 + blockIdx.x) * 64 + lanep) * 8 + (lq & 1) * 4) = pk;
  }
}

// --------------------------------------------- He partials: fragment-major
// Double-buffered LDS transpose tile, ONE barrier per 64-row step.
__global__ __launch_bounds__(512) void at_gemm_kern(const bf16_t* __restrict__ Hbp,
                                                    const bf16_t* __restrict__ Yf,
                                                    bf16_t* __restrict__ part) {
  __shared__ bf16_t T[2][128 * 72];    // [buf][e_local][64 n + pad]
  int t = threadIdx.x, l = t & 63, wv = t >> 6;
  int lr = l & 15, lq = l >> 4;
  int eh = wv >> 2, fq = wv & 3;
  int e0 = blockIdx.x * 128;
  int s0 = blockIdx.y * 20;
  int rp = t >> 4;
  int ck = t & 15;
  f32x4 acc[4][4] = {};
  const bf16_t* src = Hbp + (((long)(e0 >> 6) + (ck >> 3)) * NNP + (long)s0 * 64 + 2 * rp) * 64
                          + (ck & 7) * 8;
  bf16x8 ra = *(const bf16x8*)src;
  bf16x8 rb = *(const bf16x8*)(src + 64);
  {
    #pragma unroll
    for (int j = 0; j < 8; ++j) {
      int jj = (j + ck) & 7;
      int el = ck * 8 + jj;
      unsigned lo = (unsigned)__builtin_bit_cast(unsigned short, (__bf16)ra[jj]);
      unsigned hi = (unsigned)__builtin_bit_cast(unsigned short, (__bf16)rb[jj]);
      *(unsigned*)(&T[0][el * 72 + rp * 2]) = lo | (hi << 16);
    }
    src += 64 * 64;
    ra = *(const bf16x8*)src;
    rb = *(const bf16x8*)(src + 64);
  }
  for (int i = 0; i < 20; ++i) {
    __syncthreads();
    if (i + 1 < 20) {
      int nb = (i + 1) & 1;
      #pragma unroll
      for (int j = 0; j < 8; ++j) {
        int jj = (j + ck) & 7;
        int el = ck * 8 + jj;
        unsigned lo = (unsigned)__builtin_bit_cast(unsigned short, (__bf16)ra[jj]);
        unsigned hi = (unsigned)__builtin_bit_cast(unsigned short, (__bf16)rb[jj]);
        *(unsigned*)(&T[nb][el * 72 + rp * 2]) = lo | (hi << 16);
      }
    }
    if (i + 2 < 20) {
      src += 64 * 64;
      ra = *(const bf16x8*)src;
      rb = *(const bf16x8*)(src + 64);
    }
    int cb = i & 1;
    int s = s0 + i;
    #pragma unroll
    for (int k32 = 0; k32 < 2; ++k32) {
      bf16x8 a[4], b[4];
      #pragma unroll
      for (int ni = 0; ni < 4; ++ni)
        a[ni] = *(const bf16x8*)(&T[cb][(eh * 64 + ni * 16 + lr) * 72 + k32 * 32 + lq * 8]);
      const bf16_t* bp = Yf + ((long)(s * 2 + k32) * 64 + l) * 8;
      #pragma unroll
      for (int ni = 0; ni < 4; ++ni)
        b[ni] = *(const bf16x8*)(bp + (long)(fq * 4 + ni) * 640 * 512);
      #pragma unroll
      for (int ae = 0; ae < 4; ++ae)
        #pragma unroll
        for (int bf = 0; bf < 4; ++bf)
          acc[ae][bf] = mfma16(a[ae], b[bf], acc[ae][bf]);
    }
  }
  bf16_t* pp = part + (long)blockIdx.y * (256 * 4096);
  #pragma unroll
  for (int ae = 0; ae < 4; ++ae) {
    int eblk16 = (e0 >> 4) + eh * 4 + ae;
    #pragma unroll
    for (int bf = 0; bf < 4; ++bf) {
      int fblk = fq * 4 + bf;
      f32x4 v = acc[ae][bf];
      bf16x4 pk;
      for (int r = 0; r < 4; ++r) pk[r] = (__bf16)v[r];
      *(bf16x4*)(pp + (((long)eblk16 * 16 + fblk) * 64 + l) * 4) = pk;
    }
  }
}

// Hef[f][e] (fragment-major) = es[e] * sum_s part[s][...]
__global__ __launch_bounds__(256) void reduce_he(const bf16_t* __restrict__ part,
                                                 const float* __restrict__ es,
                                                 bf16_t* __restrict__ Hef) {
  int u = blockIdx.x * 256 + threadIdx.x;
  int lane = u & 63, tile = u >> 6;
  int fblk = tile & 15, eblk16 = tile >> 4;
  int lr = lane & 15, lq = lane >> 4;
  int e_base = eblk16 * 16 + lq * 4;
  float a0 = 0.f, a1 = 0.f, a2 = 0.f, a3 = 0.f;
  #pragma unroll
  for (int s = 0; s < AT_S; ++s) {
    bf16x4 v = *(const bf16x4*)(part + (long)s * (256 * 4096) + (long)u * 4);
    a0 += (float)v[0]; a1 += (float)v[1]; a2 += (float)v[2]; a3 += (float)v[3];
  }
  f32x4 e4 = *(const f32x4*)(es + e_base);
  bf16x4 pk;
  pk[0] = (__bf16)(a0 * e4[0]); pk[1] = (__bf16)(a1 * e4[1]);
  pk[2] = (__bf16)(a2 * e4[2]); pk[3] = (__bf16)(a3 * e4[3]);
  int eblk32 = eblk16 >> 1;
  int lanep = ((eblk16 & 1) * 2 + (lq >> 1)) * 16 + lr;
  long slot = (((long)fblk * 128 + eblk32) * 64 + lanep) * 8 + (lq & 1) * 4;
  *(bf16x4*)(Hef + slot) = pk;
}

// -------- conv out: 256 blocks x 80 rows, 8 waves, perfect CU balance -----
// CONV=1: fuse Y2 = h@th2*isd (h stays in LDS). CONV=2: fuse logits.
template<int CONV>
__global__ __launch_bounds__(512) void out_gemm_kern(const bf16_t* __restrict__ Hef,
                                                     const bf16_t* __restrict__ Hbp,
                                                     const float* __restrict__ isd,
                                                     const float* __restrict__ bias,
                                                     const bf16_t* __restrict__ th2w,
                                                     bf16_t* __restrict__ Yf,
                                                     const float* __restrict__ ow,
                                                     const float* __restrict__ ob,
                                                     float* __restrict__ out) {
  __shared__ bf16_t lbuf[2][5120];     // [buf][frag 10][lane 64][8]
  __shared__ float lgp[8][80][2];      // CONV2 logits partials
  __shared__ bf16_t hl[80 * 260];      // CONV1 h tile, stride 260 bf16
  int t = threadIdx.x, l = t & 63, wv = t >> 6;
  int lr = l & 15, lq = l >> 4;
  long r0 = (long)blockIdx.x * 80;
  f32x4 acc[5][2] = {};
  int f1 = wv, f2 = 8 + wv;
  bool has2 = wv < 2;
  const bf16_t* asrc1 = Hbp + (r0 + (f1 >> 1) * 16 + lr) * 64 + (f1 & 1) * 32 + lq * 8;
  const bf16_t* asrc2 = Hbp + (r0 + (f2 >> 1) * 16 + lr) * 64 + (f2 & 1) * 32 + lq * 8;
  const bf16_t* bbase = Hef + (long)l * 8;
  bf16x8 rg1 = *(const bf16x8*)asrc1;
  bf16x8 rg2;
  if (has2) rg2 = *(const bf16x8*)asrc2;
  int c = 0;
  for (int s = 0; s < 64; ++s) {
    *(bf16x8*)(&lbuf[c][f1 * 512 + l * 8]) = rg1;
    if (has2) *(bf16x8*)(&lbuf[c][f2 * 512 + l * 8]) = rg2;
    __syncthreads();
    if (s + 1 < 64) {
      rg1 = *(const bf16x8*)(asrc1 + (long)(s + 1) * NNP * 64);
      if (has2) rg2 = *(const bf16x8*)(asrc2 + (long)(s + 1) * NNP * 64);
    }
    #pragma unroll
    for (int k32 = 0; k32 < 2; ++k32) {
      bf16x8 a[5], b[2];
      #pragma unroll
      for (int mi = 0; mi < 5; ++mi)
        a[mi] = *(const bf16x8*)(&lbuf[c][(mi * 2 + k32) * 512 + l * 8]);
      int eblk = s * 2 + k32;
      #pragma unroll
      for (int ni = 0; ni < 2; ++ni)
        b[ni] = *(const bf16x8*)(bbase + ((long)(wv * 2 + ni) * 128 + eblk) * 512);
      #pragma unroll
      for (int mi = 0; mi < 5; ++mi) {
        acc[mi][0] = mfma16(a[mi], b[0], acc[mi][0]);
        acc[mi][1] = mfma16(a[mi], b[1], acc[mi][1]);
      }
    }
    c ^= 1;
  }
  #pragma unroll
  for (int mi = 0; mi < 5; ++mi) {
    long nb = r0 + mi * 16 + lq * 4;
    #pragma unroll
    for (int r = 0; r < 4; ++r) {
      long n = nb + r;
      float sd = (n < NN) ? isd[n] : 0.f;
      float a0 = 0.f, a1 = 0.f;
      #pragma unroll
      for (int ni = 0; ni < 2; ++ni) {
        int f = wv * 32 + ni * 16 + lr;
        float vv = acc[mi][ni][r] * sd + bias[f];
        vv = vv > 0.f ? vv : 0.f;
        if constexpr (CONV == 1) {
          hl[(mi * 16 + lq * 4 + r) * 260 + f] = (__bf16)vv;
        } else {
          a0 += vv * ow[f * 2];
          a1 += vv * ow[f * 2 + 1];
        }
      }
      if constexpr (CONV == 2) {
        #pragma unroll
        for (int m = 1; m < 16; m <<= 1) { a0 += __shfl_xor(a0, m); a1 += __shfl_xor(a1, m); }
        if (lr == 0) {
          int rowl = mi * 16 + lq * 4 + r;
          lgp[wv][rowl][0] = a0;
          lgp[wv][rowl][1] = a1;
        }
      }
    }
  }
  if constexpr (CONV == 1) {
    __syncthreads();
    f32x4 acc2[5][2] = {};
    for (int k0 = 0; k0 < 256; k0 += 32) {
      bf16x8 a_[5], b2[2];
      #pragma unroll
      for (int mi = 0; mi < 5; ++mi)
        a_[mi] = *(const bf16x8*)(hl + (mi * 16 + lr) * 260 + k0 + lq * 8);
      #pragma unroll
      for (int ni = 0; ni < 2; ++ni)
        b2[ni] = *(const bf16x8*)(th2w + (long)(wv * 32 + ni * 16 + lr) * 256 + k0 + lq * 8);
      #pragma unroll
      for (int mi = 0; mi < 5; ++mi) {
        acc2[mi][0] = mfma16(a_[mi], b2[0], acc2[mi][0]);
        acc2[mi][1] = mfma16(a_[mi], b2[1], acc2[mi][1]);
      }
    }
    #pragma unroll
    for (int mi = 0; mi < 5; ++mi) {
      long nbase = r0 + mi * 16;
      long nblk = nbase >> 5;
      int hm16 = (int)((nbase >> 4) & 1);
      int lanep = (hm16 * 2 + (lq >> 1)) * 16 + lr;
      #pragma unroll
      for (int ni = 0; ni < 2; ++ni) {
        int fblk = wv * 2 + ni;
        bf16x4 pk;
        #pragma unroll
        for (int r = 0; r < 4; ++r) {
          long n = nbase + lq * 4 + r;
          float sc = (n < NN) ? isd[n] : 0.f;
          pk[r] = (__bf16)(acc2[mi][ni][r] * sc);
        }
        *(bf16x4*)(Yf + (((long)fblk * 640 + nblk) * 64 + lanep) * 8 + (lq & 1) * 4) = pk;
      }
    }
  } else {
    __syncthreads();
    if (t < 80) {
      float s0 = 0.f, s1 = 0.f;
      #pragma unroll
      for (int wvi = 0; wvi < 8; ++wvi) { s0 += lgp[wvi][t][0]; s1 += lgp[wvi][t][1]; }
      long n = r0 + t;
      if (n < NN) {
        out[n * 2]     = s0 + ob[0];
        out[n * 2 + 1] = s1 + ob[1];
      }
    }
  }
}

// ============================================================== launcher
extern "C" void kernel_launch(void* const* d_in, const int* in_sizes, int n_in,
                              void* d_out, int out_size, void* d_ws, size_t ws_size,
                              hipStream_t stream) {
  const float* x    = (const float*)d_in[0];
  const float* z    = (const float*)d_in[1];
  const float* H    = (const float*)d_in[2];
  const float* w    = (const float*)d_in[3];
  const float* psi_w = (const float*)d_in[4];
  const float* psi_b = (const float*)d_in[5];
  const float* phi_w = (const float*)d_in[6];
  const float* phi_b = (const float*)d_in[7];
  const float* g1_w  = (const float*)d_in[8];
  const float* g1_b  = (const float*)d_in[9];
  const float* g2_w  = (const float*)d_in[10];
  const float* g2_b  = (const float*)d_in[11];
  const float* th1   = (const float*)d_in[12];
  const float* b1    = (const float*)d_in[13];
  const float* th2   = (const float*)d_in[14];
  const float* b2    = (const float*)d_in[15];
  const float* out_w = (const float*)d_in[16];
  const float* out_b = (const float*)d_in[17];

  float* logits_out = (float*)d_out;                 // [20000][2]
  float* gate_out   = logits_out + (size_t)NN * 2;   // [20000][128]

  char* p = (char*)d_ws;
  auto alloc = [&](size_t bytes) { char* r = p; p += (bytes + 255) & ~(size_t)255; return r; };
  float* Dvp  = (float*)alloc((size_t)NEB * NNP * 4);
  float* Dep  = (float*)alloc((size_t)NNB * NE * 4);
  float* isd  = (float*)alloc((size_t)NN * 4);
  float* es   = (float*)alloc((size_t)NE * 4);
  bf16_t* cat   = (bf16_t*)alloc((size_t)NN * 256 * 2);
  bf16_t* hid1  = (bf16_t*)alloc((size_t)NN * 256 * 2);
  bf16_t* Yf    = (bf16_t*)alloc((size_t)16 * 640 * 512 * 2);   // 10.49 MB
  bf16_t* Hef   = (bf16_t*)alloc((size_t)16 * 128 * 512 * 2);   // 2.1 MB
  bf16_t* pbuf  = (bf16_t*)alloc((size_t)AT_S * 256 * 4096 * 2); // 33.5 MB
  bf16_t* Hbp   = (bf16_t*)alloc((size_t)NNP * NE * 2);          // 168 MB
  bf16_t* psi_wt = (bf16_t*)alloc(65536 * 2);
  bf16_t* phi_wt = (bf16_t*)alloc(32768 * 2);
  bf16_t* g1_wt  = (bf16_t*)alloc(65536 * 2);
  bf16_t* g2_wt  = (bf16_t*)alloc(32768 * 2);
  bf16_t* th1_wt = (bf16_t*)alloc(32768 * 2);
  bf16_t* th2_wt = (bf16_t*)alloc(65536 * 2);

  cvtw_kern<<<1152, 256, 0, stream>>>(psi_w, phi_w, g1_w, g2_w, th1, th2,
                                      psi_wt, phi_wt, g1_wt, g2_wt, th1_wt, th2_wt);
  // stats + psi + phi overlapped in one launch
  fusedA_kern<<<1890, 256, 0, stream>>>(H, w, Dvp, Dep, Hbp,
                                        x, psi_wt, psi_b, z, phi_wt, phi_b, cat);
  // finalize + g1 overlapped in one launch
  fusedB_kern<<<1329, 256, 0, stream>>>(Dvp, Dep, w, isd, es,
                                        cat, g1_wt, g1_b, hid1);
  gate_y_kern<<<640, 256, 0, stream>>>(hid1, g2_wt, g2_b, cat, th1_wt, isd, gate_out, Yf);

  // hconv 1 (+ fused Y2 producer)
  at_gemm_kern<<<dim3(32, AT_S), 512, 0, stream>>>(Hbp, Yf, pbuf);
  reduce_he<<<1024, 256, 0, stream>>>(pbuf, es, Hef);
  out_gemm_kern<1><<<256, 512, 0, stream>>>(Hef, Hbp, isd, b1, th2_wt, Yf,
                                            nullptr, nullptr, nullptr);

  // hconv 2 (+ fused logits)
  at_gemm_kern<<<dim3(32, AT_S), 512, 0, stream>>>(Hbp, Yf, pbuf);
  reduce_he<<<1024, 256, 0, stream>>>(pbuf, es, Hef);
  out_gemm_kern<2><<<256, 512, 0, stream>>>(Hef, Hbp, isd, b2, nullptr, nullptr,
                                            out_w, out_b, logits_out);

  (void)in_sizes; (void)n_in; (void)out_size; (void)ws_size;
}